// Round 10
// baseline (533.744 us; speedup 1.0000x reference)
//
#include <hip/hip_runtime.h>

#define N_NODES 100000
#define N_EDGES 3200000
#define IN_DIM  128
#define HID     16
#define OUTC    2

// bucket geometry
#define NB     128                    // dst-range buckets
#define SPAN   782                    // nodes per bucket (128*782 = 100096 >= N)
#define CAP    26500                  // per-bucket capacity (mean 25000)
#define NBLK   256                    // bucketing blocks
#define BLK_E  (N_EDGES / NBLK)       // 12500 edges per block

// ---------------- K1a: per-(block,bucket) counts ----------------
__global__ __launch_bounds__(256) void k_count_bb(const int* __restrict__ dst,
                                                  int* __restrict__ bc) {
    __shared__ int h[NB];
    if (threadIdx.x < NB) h[threadIdx.x] = 0;
    __syncthreads();
    const int4* d4 = (const int4*)(dst + blockIdx.x * BLK_E);
    for (int i = threadIdx.x; i < BLK_E / 4; i += 256) {
        int4 v = d4[i];
        atomicAdd(&h[(unsigned)v.x / SPAN], 1);
        atomicAdd(&h[(unsigned)v.y / SPAN], 1);
        atomicAdd(&h[(unsigned)v.z / SPAN], 1);
        atomicAdd(&h[(unsigned)v.w / SPAN], 1);
    }
    __syncthreads();
    if (threadIdx.x < NB) bc[blockIdx.x * NB + threadIdx.x] = h[threadIdx.x];
}

// ---------------- K1b: in-place exclusive scan per bucket over blocks ----------------
__global__ __launch_bounds__(128) void k_scan_bb(int* __restrict__ bc,
                                                 int* __restrict__ bcount) {
    int b = threadIdx.x;   // one thread per bucket; reads are coalesced across threads
    int run = 0;
    for (int blk = 0; blk < NBLK; ++blk) {
        int v = bc[blk * NB + b];
        bc[blk * NB + b] = run;
        run += v;
    }
    bcount[b] = run;
}

// ---------------- K1c: fill buckets (LDS-ranked, atomic-free globally) ----------------
__global__ __launch_bounds__(256) void k_fillbkt(const int* __restrict__ src,
                                                 const int* __restrict__ dst,
                                                 const int* __restrict__ bc,
                                                 int* __restrict__ bsrc,
                                                 int* __restrict__ bdst) {
    __shared__ int h[NB];
    __shared__ int gb[NB];
    if (threadIdx.x < NB) {
        h[threadIdx.x] = 0;
        gb[threadIdx.x] = threadIdx.x * CAP + bc[blockIdx.x * NB + threadIdx.x];
    }
    __syncthreads();
    const int4* d4 = (const int4*)(dst + blockIdx.x * BLK_E);
    const int4* s4 = (const int4*)(src + blockIdx.x * BLK_E);
    for (int i = threadIdx.x; i < BLK_E / 4; i += 256) {
        int4 dv = d4[i];
        int4 sv = s4[i];
        int b0 = (unsigned)dv.x / SPAN; int p0 = gb[b0] + atomicAdd(&h[b0], 1); bsrc[p0] = sv.x; bdst[p0] = dv.x;
        int b1 = (unsigned)dv.y / SPAN; int p1 = gb[b1] + atomicAdd(&h[b1], 1); bsrc[p1] = sv.y; bdst[p1] = dv.y;
        int b2 = (unsigned)dv.z / SPAN; int p2 = gb[b2] + atomicAdd(&h[b2], 1); bsrc[p2] = sv.z; bdst[p2] = dv.z;
        int b3 = (unsigned)dv.w / SPAN; int p3 = gb[b3] + atomicAdd(&h[b3], 1); bsrc[p3] = sv.w; bdst[p3] = dv.w;
    }
}

// ---------------- K2: per-node degree via per-bucket LDS histogram ----------------
__global__ __launch_bounds__(256) void k_cnt_nodes(const int* __restrict__ bdst,
                                                   const int* __restrict__ bcount,
                                                   int* __restrict__ pcnt) {
    __shared__ int h[SPAN];
    int b = blockIdx.x >> 1, s = blockIdx.x & 1;
    for (int i = threadIdx.x; i < SPAN; i += 256) h[i] = 0;
    __syncthreads();
    int tot = bcount[b];
    int half = (tot + 1) >> 1;
    int lo = s ? half : 0, hi = s ? tot : half;
    const int* bd = bdst + b * CAP;
    int base = b * SPAN;
    for (int i = lo + threadIdx.x; i < hi; i += 256)
        atomicAdd(&h[bd[i] - base], 1);
    __syncthreads();
    for (int i = threadIdx.x; i < SPAN; i += 256)
        pcnt[blockIdx.x * SPAN + i] = h[i];
}

// ---------------- K2b: dinv ----------------
__global__ __launch_bounds__(256) void k_dinvk(const int* __restrict__ pcnt,
                                               float* __restrict__ dinv) {
    int n = blockIdx.x * 256 + threadIdx.x;
    if (n >= N_NODES) return;
    unsigned b = (unsigned)n / SPAN, l = n - b * SPAN;
    int c = pcnt[(2 * b) * SPAN + l] + pcnt[(2 * b + 1) * SPAN + l];
    dinv[n] = rsqrtf(1.0f + (float)c);   // + self-loop
}

// ---------------- K3: p1 = dinv * (x @ W1) ----------------
__global__ __launch_bounds__(256) void k_gemm1(const float* __restrict__ x,
                                               const float* __restrict__ W1,
                                               const float* __restrict__ dinv,
                                               float* __restrict__ p1) {
    __shared__ float sW[IN_DIM * HID];
    for (int i = threadIdx.x; i < IN_DIM * HID; i += 256) sW[i] = W1[i];
    __syncthreads();

    int gid = blockIdx.x * 256 + threadIdx.x;
    int n = gid >> 4;
    int k = gid & 15;
    if (n >= N_NODES) return;

    const float* xr = x + (size_t)n * IN_DIM;
    float acc = 0.f;
#pragma unroll 8
    for (int j = 0; j < IN_DIM; ++j)
        acc = fmaf(xr[j], sW[j * HID + k], acc);

    p1[n * HID + k] = acc * dinv[n];
}

// ---------------- K4: layer-1 aggregation into LDS accumulators ----------------
__global__ __launch_bounds__(256) void k_agg1(const int* __restrict__ bsrc,
                                              const int* __restrict__ bdst,
                                              const int* __restrict__ bcount,
                                              const float* __restrict__ p1,
                                              float* __restrict__ partial1) {
    __shared__ float acc[SPAN * HID];            // 50048 B
    int b = blockIdx.x >> 1, s = blockIdx.x & 1;
    for (int i = threadIdx.x; i < SPAN * HID; i += 256) acc[i] = 0.f;
    __syncthreads();
    int tot = bcount[b];
    int half = (tot + 1) >> 1;
    int lo = s ? half : 0, hi = s ? tot : half;
    int base = b * SPAN;
    int k = threadIdx.x & 15;
    const int* bd = bdst + b * CAP;
    const int* bs = bsrc + b * CAP;
    for (int i = lo + (threadIdx.x >> 4); i < hi; i += 16) {
        int d = bd[i];                            // 16 lanes same addr -> broadcast
        int sn = bs[i];
        atomicAdd(&acc[(d - base) * HID + k], p1[sn * HID + k]);
    }
    __syncthreads();
    float* op = partial1 + (size_t)blockIdx.x * (SPAN * HID);
    for (int i = threadIdx.x; i < SPAN * HID; i += 256) op[i] = acc[i];
}

// ---------------- K4b: merge + self + relu/b1 + @W2 -> p2b ----------------
__global__ __launch_bounds__(256) void k_fin1(const float* __restrict__ partial1,
                                              const float* __restrict__ p1,
                                              const float* __restrict__ dinv,
                                              const float* __restrict__ b1,
                                              const float* __restrict__ W2,
                                              float* __restrict__ p2b) {
    int gid = blockIdx.x * 256 + threadIdx.x;
    int n = gid >> 4, k = gid & 15;
    if (n >= N_NODES) return;
    unsigned b = (unsigned)n / SPAN, l = n - b * SPAN;
    float a = partial1[(size_t)(2 * b) * (SPAN * HID) + l * HID + k]
            + partial1[(size_t)(2 * b + 1) * (SPAN * HID) + l * HID + k]
            + p1[n * HID + k];                   // self-loop
    float di = dinv[n];
    float h = fmaxf(fmaf(di, a, b1[k]), 0.f);
    float hv = di * h;
    float t0 = hv * W2[k * OUTC + 0];
    float t1 = hv * W2[k * OUTC + 1];
#pragma unroll
    for (int m = 1; m < HID; m <<= 1) {
        t0 += __shfl_xor(t0, m);
        t1 += __shfl_xor(t1, m);
    }
    if (k == 0) *(float2*)(p2b + n * OUTC) = make_float2(t0, t1);
}

// ---------------- K5: layer-2 aggregation (float2) ----------------
__global__ __launch_bounds__(256) void k_agg2(const int* __restrict__ bsrc,
                                              const int* __restrict__ bdst,
                                              const int* __restrict__ bcount,
                                              const float* __restrict__ p2b,
                                              float* __restrict__ partial2) {
    __shared__ float acc[SPAN * 2];
    int b = blockIdx.x >> 1, s = blockIdx.x & 1;
    for (int i = threadIdx.x; i < SPAN * 2; i += 256) acc[i] = 0.f;
    __syncthreads();
    int tot = bcount[b];
    int half = (tot + 1) >> 1;
    int lo = s ? half : 0, hi = s ? tot : half;
    int base = b * SPAN;
    int c = threadIdx.x & 1;
    const int* bd = bdst + b * CAP;
    const int* bs = bsrc + b * CAP;
    for (int i = lo + (threadIdx.x >> 1); i < hi; i += 128) {
        int d = bd[i];
        int sn = bs[i];
        atomicAdd(&acc[(d - base) * 2 + c], p2b[sn * 2 + c]);
    }
    __syncthreads();
    float* op = partial2 + (size_t)blockIdx.x * (SPAN * 2);
    for (int i = threadIdx.x; i < SPAN * 2; i += 256) op[i] = acc[i];
}

// ---------------- K5b: merge + self + b2 + log_softmax ----------------
__global__ __launch_bounds__(256) void k_fin2(const float* __restrict__ partial2,
                                              const float* __restrict__ p2b,
                                              const float* __restrict__ dinv,
                                              const float* __restrict__ b2,
                                              float* __restrict__ out) {
    int n = blockIdx.x * 256 + threadIdx.x;
    if (n >= N_NODES) return;
    unsigned b = (unsigned)n / SPAN, l = n - b * SPAN;
    const float* q0 = partial2 + (size_t)(2 * b) * (SPAN * 2) + l * 2;
    const float* q1 = partial2 + (size_t)(2 * b + 1) * (SPAN * 2) + l * 2;
    float a0 = q0[0] + q1[0] + p2b[n * 2 + 0];
    float a1 = q0[1] + q1[1] + p2b[n * 2 + 1];
    float di = dinv[n];
    float v0 = fmaf(di, a0, b2[0]);
    float v1 = fmaf(di, a1, b2[1]);
    float mx = fmaxf(v0, v1);
    float lse = mx + logf(expf(v0 - mx) + expf(v1 - mx));
    *(float2*)(out + n * 2) = make_float2(v0 - lse, v1 - lse);
}

extern "C" void kernel_launch(void* const* d_in, const int* in_sizes, int n_in,
                              void* d_out, int out_size, void* d_ws, size_t ws_size,
                              hipStream_t stream) {
    const float* x  = (const float*)d_in[0];
    const int*   ei = (const int*)d_in[1];
    const float* W1 = (const float*)d_in[2];
    const float* b1 = (const float*)d_in[3];
    const float* W2 = (const float*)d_in[4];
    const float* b2 = (const float*)d_in[5];
    float* out = (float*)d_out;

    const int* src = ei;             // edge_index[0]
    const int* dst = ei + N_EDGES;   // edge_index[1]

    // workspace layout (4B elements)
    int* bc       = (int*)d_ws;                        // 256*128
    int* bcount   = bc + NBLK * NB;                    // 128
    int* bsrc     = bcount + NB;                       // NB*CAP = 3,392,000
    int* bdst     = bsrc + NB * CAP;                   // 3,392,000
    int* pcnt     = bdst + NB * CAP;                   // 256*SPAN
    float* dinv   = (float*)(pcnt + 2 * NB * SPAN);    // 100,000
    float* p1     = dinv + N_NODES;                    // 1,600,000
    float* part1  = p1 + (size_t)N_NODES * HID;        // 256*SPAN*HID = 3,203,072
    float* p2b    = part1 + (size_t)2 * NB * SPAN * HID; // 200,000
    float* part2  = p2b + (size_t)N_NODES * OUTC;      // 256*SPAN*2

    k_count_bb <<<NBLK, 256, 0, stream>>>(dst, bc);
    k_scan_bb  <<<1, 128, 0, stream>>>(bc, bcount);
    k_fillbkt  <<<NBLK, 256, 0, stream>>>(src, dst, bc, bsrc, bdst);
    k_cnt_nodes<<<2 * NB, 256, 0, stream>>>(bdst, bcount, pcnt);
    k_dinvk    <<<(N_NODES + 255) / 256, 256, 0, stream>>>(pcnt, dinv);
    k_gemm1    <<<(N_NODES * 16 + 255) / 256, 256, 0, stream>>>(x, W1, dinv, p1);
    k_agg1     <<<2 * NB, 256, 0, stream>>>(bsrc, bdst, bcount, p1, part1);
    k_fin1     <<<(N_NODES * 16 + 255) / 256, 256, 0, stream>>>(part1, p1, dinv, b1, W2, p2b);
    k_agg2     <<<2 * NB, 256, 0, stream>>>(bsrc, bdst, bcount, p2b, part2);
    k_fin2     <<<(N_NODES + 255) / 256, 256, 0, stream>>>(part2, p2b, dinv, b2, out);
}

// Round 11
// 388.180 us; speedup vs baseline: 1.3750x; 1.3750x over previous
//
#include <hip/hip_runtime.h>

#define N_NODES 100000
#define N_EDGES 3200000
#define IN_DIM  128
#define HID     16
#define OUTC    2

// bucket geometry
#define NB     128                    // dst-range buckets
#define SPAN   782                    // nodes per bucket (128*782 = 100096 >= N)
#define CAP    26500                  // per-bucket capacity (mean 25000)
#define NBLK   256                    // bucketing blocks
#define BLK_E  (N_EDGES / NBLK)       // 12500 edges per block
#define S0     8                      // splits per bucket: degree count
#define S1     4                      // splits per bucket: layer-1 agg
#define S2     8                      // splits per bucket: layer-2 agg

// ---------------- K1a: per-(block,bucket) counts ----------------
__global__ __launch_bounds__(256) void k_count_bb(const int* __restrict__ dst,
                                                  int* __restrict__ bc) {
    __shared__ int h[NB];
    if (threadIdx.x < NB) h[threadIdx.x] = 0;
    __syncthreads();
    const int4* d4 = (const int4*)(dst + blockIdx.x * BLK_E);
    for (int i = threadIdx.x; i < BLK_E / 4; i += 256) {
        int4 v = d4[i];
        atomicAdd(&h[(unsigned)v.x / SPAN], 1);
        atomicAdd(&h[(unsigned)v.y / SPAN], 1);
        atomicAdd(&h[(unsigned)v.z / SPAN], 1);
        atomicAdd(&h[(unsigned)v.w / SPAN], 1);
    }
    __syncthreads();
    if (threadIdx.x < NB) bc[blockIdx.x * NB + threadIdx.x] = h[threadIdx.x];
}

// ---------------- K1b: in-place exclusive scan per bucket over blocks ----------------
__global__ __launch_bounds__(128) void k_scan_bb(int* __restrict__ bc,
                                                 int* __restrict__ bcount) {
    int b = threadIdx.x;   // coalesced across threads
    int run = 0;
    for (int blk = 0; blk < NBLK; ++blk) {
        int v = bc[blk * NB + b];
        bc[blk * NB + b] = run;
        run += v;
    }
    bcount[b] = run;
}

// ---------------- K1c: fill buckets (LDS-ranked, atomic-free globally) ----------------
__global__ __launch_bounds__(256) void k_fillbkt(const int* __restrict__ src,
                                                 const int* __restrict__ dst,
                                                 const int* __restrict__ bc,
                                                 int* __restrict__ bsrc,
                                                 int* __restrict__ bdst) {
    __shared__ int h[NB];
    __shared__ int gb[NB];
    if (threadIdx.x < NB) {
        h[threadIdx.x] = 0;
        gb[threadIdx.x] = threadIdx.x * CAP + bc[blockIdx.x * NB + threadIdx.x];
    }
    __syncthreads();
    const int4* d4 = (const int4*)(dst + blockIdx.x * BLK_E);
    const int4* s4 = (const int4*)(src + blockIdx.x * BLK_E);
    for (int i = threadIdx.x; i < BLK_E / 4; i += 256) {
        int4 dv = d4[i];
        int4 sv = s4[i];
        int b0 = (unsigned)dv.x / SPAN; int p0 = gb[b0] + atomicAdd(&h[b0], 1); bsrc[p0] = sv.x; bdst[p0] = dv.x;
        int b1 = (unsigned)dv.y / SPAN; int p1 = gb[b1] + atomicAdd(&h[b1], 1); bsrc[p1] = sv.y; bdst[p1] = dv.y;
        int b2 = (unsigned)dv.z / SPAN; int p2 = gb[b2] + atomicAdd(&h[b2], 1); bsrc[p2] = sv.z; bdst[p2] = dv.z;
        int b3 = (unsigned)dv.w / SPAN; int p3 = gb[b3] + atomicAdd(&h[b3], 1); bsrc[p3] = sv.w; bdst[p3] = dv.w;
    }
}

// ---------------- K2: per-node degree, S0 splits per bucket ----------------
__global__ __launch_bounds__(256) void k_cnt_nodes(const int* __restrict__ bdst,
                                                   const int* __restrict__ bcount,
                                                   int* __restrict__ pcnt) {
    __shared__ int h[SPAN];
    int b = blockIdx.x / S0, s = blockIdx.x % S0;
    for (int i = threadIdx.x; i < SPAN; i += 256) h[i] = 0;
    __syncthreads();
    int tot = bcount[b];
    int lo = tot * s / S0, hi = tot * (s + 1) / S0;
    const int* bd = bdst + b * CAP;
    int base = b * SPAN;
    int i = lo + threadIdx.x;
    for (; i + 256 < hi; i += 512) {
        int d0 = bd[i], d1 = bd[i + 256];
        atomicAdd(&h[d0 - base], 1);
        atomicAdd(&h[d1 - base], 1);
    }
    if (i < hi) atomicAdd(&h[bd[i] - base], 1);
    __syncthreads();
    for (int j = threadIdx.x; j < SPAN; j += 256)
        pcnt[blockIdx.x * SPAN + j] = h[j];
}

// ---------------- K2b: dinv ----------------
__global__ __launch_bounds__(256) void k_dinvk(const int* __restrict__ pcnt,
                                               float* __restrict__ dinv) {
    int n = blockIdx.x * 256 + threadIdx.x;
    if (n >= N_NODES) return;
    unsigned b = (unsigned)n / SPAN, l = n - b * SPAN;
    int c = 0;
#pragma unroll
    for (int s = 0; s < S0; ++s)
        c += pcnt[(b * S0 + s) * SPAN + l];
    dinv[n] = rsqrtf(1.0f + (float)c);   // + self-loop
}

// ---------------- K3: p1 = dinv * (x @ W1) ----------------
__global__ __launch_bounds__(256) void k_gemm1(const float* __restrict__ x,
                                               const float* __restrict__ W1,
                                               const float* __restrict__ dinv,
                                               float* __restrict__ p1) {
    __shared__ float sW[IN_DIM * HID];
    for (int i = threadIdx.x; i < IN_DIM * HID; i += 256) sW[i] = W1[i];
    __syncthreads();

    int gid = blockIdx.x * 256 + threadIdx.x;
    int n = gid >> 4;
    int k = gid & 15;
    if (n >= N_NODES) return;

    const float* xr = x + (size_t)n * IN_DIM;
    float acc = 0.f;
#pragma unroll 8
    for (int j = 0; j < IN_DIM; ++j)
        acc = fmaf(xr[j], sW[j * HID + k], acc);

    p1[n * HID + k] = acc * dinv[n];
}

// ---------------- K4: layer-1 aggregation, S1 splits per bucket ----------------
__global__ __launch_bounds__(256) void k_agg1(const int* __restrict__ bsrc,
                                              const int* __restrict__ bdst,
                                              const int* __restrict__ bcount,
                                              const float* __restrict__ p1,
                                              float* __restrict__ partial1) {
    __shared__ float acc[SPAN * HID];            // 50048 B
    int b = blockIdx.x / S1, s = blockIdx.x % S1;
    for (int i = threadIdx.x; i < SPAN * HID; i += 256) acc[i] = 0.f;
    __syncthreads();
    int tot = bcount[b];
    int lo = tot * s / S1, hi = tot * (s + 1) / S1;
    int base = b * SPAN;
    int k = threadIdx.x & 15;
    int g = threadIdx.x >> 4;                    // 16 edge-groups per block
    const int* bd = bdst + b * CAP;
    const int* bs = bsrc + b * CAP;
    int i = lo + g;
    for (; i + 16 < hi; i += 32) {               // 2 independent gathers in flight
        int d0 = bd[i],      s0 = bs[i];
        int d1 = bd[i + 16], s1 = bs[i + 16];
        float v0 = p1[s0 * HID + k];
        float v1 = p1[s1 * HID + k];
        atomicAdd(&acc[(d0 - base) * HID + k], v0);
        atomicAdd(&acc[(d1 - base) * HID + k], v1);
    }
    if (i < hi) {
        int d = bd[i], sn = bs[i];
        atomicAdd(&acc[(d - base) * HID + k], p1[sn * HID + k]);
    }
    __syncthreads();
    float* op = partial1 + (size_t)blockIdx.x * (SPAN * HID);
    for (int j = threadIdx.x; j < SPAN * HID; j += 256) op[j] = acc[j];
}

// ---------------- K4b: merge S1 partials + self + relu/b1 + @W2 -> p2b ----------------
__global__ __launch_bounds__(256) void k_fin1(const float* __restrict__ partial1,
                                              const float* __restrict__ p1,
                                              const float* __restrict__ dinv,
                                              const float* __restrict__ b1,
                                              const float* __restrict__ W2,
                                              float* __restrict__ p2b) {
    int gid = blockIdx.x * 256 + threadIdx.x;
    int n = gid >> 4, k = gid & 15;
    if (n >= N_NODES) return;
    unsigned b = (unsigned)n / SPAN, l = n - b * SPAN;
    float a = p1[n * HID + k];                   // self-loop
#pragma unroll
    for (int s = 0; s < S1; ++s)
        a += partial1[(size_t)(b * S1 + s) * (SPAN * HID) + l * HID + k];
    float di = dinv[n];
    float h = fmaxf(fmaf(di, a, b1[k]), 0.f);
    float hv = di * h;
    float t0 = hv * W2[k * OUTC + 0];
    float t1 = hv * W2[k * OUTC + 1];
#pragma unroll
    for (int m = 1; m < HID; m <<= 1) {
        t0 += __shfl_xor(t0, m);
        t1 += __shfl_xor(t1, m);
    }
    if (k == 0) *(float2*)(p2b + n * OUTC) = make_float2(t0, t1);
}

// ---------------- K5: layer-2 aggregation (float2), S2 splits ----------------
__global__ __launch_bounds__(256) void k_agg2(const int* __restrict__ bsrc,
                                              const int* __restrict__ bdst,
                                              const int* __restrict__ bcount,
                                              const float* __restrict__ p2b,
                                              float* __restrict__ partial2) {
    __shared__ float acc[SPAN * 2];
    int b = blockIdx.x / S2, s = blockIdx.x % S2;
    for (int i = threadIdx.x; i < SPAN * 2; i += 256) acc[i] = 0.f;
    __syncthreads();
    int tot = bcount[b];
    int lo = tot * s / S2, hi = tot * (s + 1) / S2;
    int base = b * SPAN;
    int c = threadIdx.x & 1;
    int g = threadIdx.x >> 1;                    // 128 edge-groups
    const int* bd = bdst + b * CAP;
    const int* bs = bsrc + b * CAP;
    int i = lo + g;
    for (; i + 128 < hi; i += 256) {
        int d0 = bd[i],       s0 = bs[i];
        int d1 = bd[i + 128], s1 = bs[i + 128];
        float v0 = p2b[s0 * 2 + c];
        float v1 = p2b[s1 * 2 + c];
        atomicAdd(&acc[(d0 - base) * 2 + c], v0);
        atomicAdd(&acc[(d1 - base) * 2 + c], v1);
    }
    if (i < hi) {
        int d = bd[i], sn = bs[i];
        atomicAdd(&acc[(d - base) * 2 + c], p2b[sn * 2 + c]);
    }
    __syncthreads();
    float* op = partial2 + (size_t)blockIdx.x * (SPAN * 2);
    for (int j = threadIdx.x; j < SPAN * 2; j += 256) op[j] = acc[j];
}

// ---------------- K5b: merge S2 partials + self + b2 + log_softmax ----------------
__global__ __launch_bounds__(256) void k_fin2(const float* __restrict__ partial2,
                                              const float* __restrict__ p2b,
                                              const float* __restrict__ dinv,
                                              const float* __restrict__ b2,
                                              float* __restrict__ out) {
    int n = blockIdx.x * 256 + threadIdx.x;
    if (n >= N_NODES) return;
    unsigned b = (unsigned)n / SPAN, l = n - b * SPAN;
    float a0 = p2b[n * 2 + 0];
    float a1 = p2b[n * 2 + 1];
#pragma unroll
    for (int s = 0; s < S2; ++s) {
        const float* q = partial2 + (size_t)(b * S2 + s) * (SPAN * 2) + l * 2;
        a0 += q[0];
        a1 += q[1];
    }
    float di = dinv[n];
    float v0 = fmaf(di, a0, b2[0]);
    float v1 = fmaf(di, a1, b2[1]);
    float mx = fmaxf(v0, v1);
    float lse = mx + logf(expf(v0 - mx) + expf(v1 - mx));
    *(float2*)(out + n * 2) = make_float2(v0 - lse, v1 - lse);
}

extern "C" void kernel_launch(void* const* d_in, const int* in_sizes, int n_in,
                              void* d_out, int out_size, void* d_ws, size_t ws_size,
                              hipStream_t stream) {
    const float* x  = (const float*)d_in[0];
    const int*   ei = (const int*)d_in[1];
    const float* W1 = (const float*)d_in[2];
    const float* b1 = (const float*)d_in[3];
    const float* W2 = (const float*)d_in[4];
    const float* b2 = (const float*)d_in[5];
    float* out = (float*)d_out;

    const int* src = ei;             // edge_index[0]
    const int* dst = ei + N_EDGES;   // edge_index[1]

    // workspace layout (4B elements)
    int* bc       = (int*)d_ws;                          // 32768
    int* bcount   = bc + NBLK * NB;                      // 128
    int* bsrc     = bcount + NB;                         // NB*CAP = 3,392,000 (13.6 MB)
    int* bdst     = bsrc + NB * CAP;                     // 13.6 MB
    float* dinv   = (float*)(bdst + NB * CAP);           // 0.4 MB
    float* p1     = dinv + N_NODES;                      // 6.4 MB
    float* p2b    = p1 + (size_t)N_NODES * HID;          // 0.8 MB
    // big region: partial1 (25.6 MB); pcnt and partial2 alias its head
    float* partial1 = p2b + (size_t)N_NODES * OUTC;      // S1*NB*SPAN*HID = 6,406,144 f
    int*   pcnt     = (int*)partial1;                    // S0*NB*SPAN = 800,768 i  (dead before agg1)
    float* partial2 = partial1;                          // S2*NB*SPAN*2 = 1,601,536 f (after fin1)

    k_count_bb <<<NBLK, 256, 0, stream>>>(dst, bc);
    k_scan_bb  <<<1, 128, 0, stream>>>(bc, bcount);
    k_fillbkt  <<<NBLK, 256, 0, stream>>>(src, dst, bc, bsrc, bdst);
    k_cnt_nodes<<<NB * S0, 256, 0, stream>>>(bdst, bcount, pcnt);
    k_dinvk    <<<(N_NODES + 255) / 256, 256, 0, stream>>>(pcnt, dinv);
    k_gemm1    <<<(N_NODES * 16 + 255) / 256, 256, 0, stream>>>(x, W1, dinv, p1);
    k_agg1     <<<NB * S1, 256, 0, stream>>>(bsrc, bdst, bcount, p1, partial1);   // pcnt dead
    k_fin1     <<<(N_NODES * 16 + 255) / 256, 256, 0, stream>>>(partial1, p1, dinv, b1, W2, p2b);
    k_agg2     <<<NB * S2, 256, 0, stream>>>(bsrc, bdst, bcount, p2b, partial2);  // partial1 dead
    k_fin2     <<<(N_NODES + 255) / 256, 256, 0, stream>>>(partial2, p2b, dinv, b2, out);
}

// Round 12
// 198.969 us; speedup vs baseline: 2.6825x; 1.9510x over previous
//
#include <hip/hip_runtime.h>

#define N_NODES 100000
#define N_EDGES 3200000
#define IN_DIM  128
#define HID     16
#define OUTC    2

// bucket geometry
#define NB     128                    // dst-range buckets
#define SPAN   782                    // nodes per bucket (128*782 >= N)
#define CAP    26500                  // per-bucket capacity
#define NBLK   256                    // bucketing blocks
#define BLK_E  (N_EDGES / NBLK)       // 12500
#define S0     8                      // splits per bucket (hist + csrfill)

// node-scan geometry
#define SCAN_ELEMS 2048
#define SCAN_NB    49                 // ceil(100000/2048)

// ---------------- K1a: per-(block,bucket) counts ----------------
__global__ __launch_bounds__(256) void k_count_bb(const int* __restrict__ dst,
                                                  int* __restrict__ bc) {
    __shared__ int h[NB];
    if (threadIdx.x < NB) h[threadIdx.x] = 0;
    __syncthreads();
    const int4* d4 = (const int4*)(dst + blockIdx.x * BLK_E);
    for (int i = threadIdx.x; i < BLK_E / 4; i += 256) {
        int4 v = d4[i];
        atomicAdd(&h[(unsigned)v.x / SPAN], 1);
        atomicAdd(&h[(unsigned)v.y / SPAN], 1);
        atomicAdd(&h[(unsigned)v.z / SPAN], 1);
        atomicAdd(&h[(unsigned)v.w / SPAN], 1);
    }
    __syncthreads();
    if (threadIdx.x < NB) bc[blockIdx.x * NB + threadIdx.x] = h[threadIdx.x];
}

// ---------------- K1b: exclusive scan per bucket over blocks ----------------
__global__ __launch_bounds__(128) void k_scan_bb(int* __restrict__ bc,
                                                 int* __restrict__ bcount) {
    int b = threadIdx.x;
    int run = 0;
    for (int blk = 0; blk < NBLK; ++blk) {
        int v = bc[blk * NB + b];
        bc[blk * NB + b] = run;
        run += v;
    }
    bcount[b] = run;
}

// ---------------- K1c: fill buckets ----------------
__global__ __launch_bounds__(256) void k_fillbkt(const int* __restrict__ src,
                                                 const int* __restrict__ dst,
                                                 const int* __restrict__ bc,
                                                 int* __restrict__ bsrc,
                                                 int* __restrict__ bdst) {
    __shared__ int h[NB];
    __shared__ int gb[NB];
    if (threadIdx.x < NB) {
        h[threadIdx.x] = 0;
        gb[threadIdx.x] = threadIdx.x * CAP + bc[blockIdx.x * NB + threadIdx.x];
    }
    __syncthreads();
    const int4* d4 = (const int4*)(dst + blockIdx.x * BLK_E);
    const int4* s4 = (const int4*)(src + blockIdx.x * BLK_E);
    for (int i = threadIdx.x; i < BLK_E / 4; i += 256) {
        int4 dv = d4[i];
        int4 sv = s4[i];
        int b0 = (unsigned)dv.x / SPAN; int p0 = gb[b0] + atomicAdd(&h[b0], 1); bsrc[p0] = sv.x; bdst[p0] = dv.x;
        int b1 = (unsigned)dv.y / SPAN; int p1 = gb[b1] + atomicAdd(&h[b1], 1); bsrc[p1] = sv.y; bdst[p1] = dv.y;
        int b2 = (unsigned)dv.z / SPAN; int p2 = gb[b2] + atomicAdd(&h[b2], 1); bsrc[p2] = sv.z; bdst[p2] = dv.z;
        int b3 = (unsigned)dv.w / SPAN; int p3 = gb[b3] + atomicAdd(&h[b3], 1); bsrc[p3] = sv.w; bdst[p3] = dv.w;
    }
}

// ---------------- K2: per-node degree histogram, S0 splits ----------------
__global__ __launch_bounds__(256) void k_cnt_nodes(const int* __restrict__ bdst,
                                                   const int* __restrict__ bcount,
                                                   int* __restrict__ pcnt) {
    __shared__ int h[SPAN];
    int b = blockIdx.x / S0, s = blockIdx.x % S0;
    for (int i = threadIdx.x; i < SPAN; i += 256) h[i] = 0;
    __syncthreads();
    int tot = bcount[b];
    int lo = tot * s / S0, hi = tot * (s + 1) / S0;
    const int* bd = bdst + b * CAP;
    int base = b * SPAN;
    for (int i = lo + threadIdx.x; i < hi; i += 256)
        atomicAdd(&h[bd[i] - base], 1);
    __syncthreads();
    for (int j = threadIdx.x; j < SPAN; j += 256)
        pcnt[blockIdx.x * SPAN + j] = h[j];
}

// ---------------- K2b: cnt + dinv ----------------
__global__ __launch_bounds__(256) void k_cntsum(const int* __restrict__ pcnt,
                                                int* __restrict__ cnt,
                                                float* __restrict__ dinv) {
    int n = blockIdx.x * 256 + threadIdx.x;
    if (n >= N_NODES) return;
    unsigned b = (unsigned)n / SPAN, l = n - b * SPAN;
    int c = 0;
#pragma unroll
    for (int s = 0; s < S0; ++s)
        c += pcnt[(b * S0 + s) * SPAN + l];
    cnt[n] = c;
    dinv[n] = rsqrtf(1.0f + (float)c);   // + self-loop
}

// ---------------- node scan (a/b/c): off = exclusive scan of cnt ----------------
__global__ __launch_bounds__(256) void k_blocksum(const int* __restrict__ cnt,
                                                  int* __restrict__ bsum) {
    __shared__ int s[256];
    int base = blockIdx.x * SCAN_ELEMS + threadIdx.x * 8;
    int t = 0;
#pragma unroll
    for (int i = 0; i < 8; ++i) {
        int idx = base + i;
        t += (idx < N_NODES) ? cnt[idx] : 0;
    }
    s[threadIdx.x] = t;
    __syncthreads();
    for (int ofs = 128; ofs > 0; ofs >>= 1) {
        if (threadIdx.x < ofs) s[threadIdx.x] += s[threadIdx.x + ofs];
        __syncthreads();
    }
    if (threadIdx.x == 0) bsum[blockIdx.x] = s[0];
}

__global__ __launch_bounds__(64) void k_scanb(const int* __restrict__ bsum,
                                              int* __restrict__ boff) {
    if (threadIdx.x == 0) {
        int run = 0;
        for (int b = 0; b < SCAN_NB; ++b) { boff[b] = run; run += bsum[b]; }
    }
}

__global__ __launch_bounds__(256) void k_offsets(const int* __restrict__ cnt,
                                                 const int* __restrict__ boff,
                                                 int* __restrict__ off) {
    __shared__ int s[256];
    int base = blockIdx.x * SCAN_ELEMS + threadIdx.x * 8;
    int c[8];
    int tsum = 0;
#pragma unroll
    for (int i = 0; i < 8; ++i) {
        int idx = base + i;
        c[i] = (idx < N_NODES) ? cnt[idx] : 0;
        tsum += c[i];
    }
    s[threadIdx.x] = tsum;
    __syncthreads();
    for (int ofs = 1; ofs < 256; ofs <<= 1) {
        int v = (threadIdx.x >= ofs) ? s[threadIdx.x - ofs] : 0;
        __syncthreads();
        s[threadIdx.x] += v;
        __syncthreads();
    }
    int tbase = boff[blockIdx.x] + s[threadIdx.x] - tsum;
    int run = 0;
#pragma unroll
    for (int i = 0; i < 8; ++i) {
        int idx = base + i;
        if (idx < N_NODES) off[idx] = tbase + run;
        run += c[i];
    }
}

// ---------------- K2c: pcnt -> per-(split,node) csr write base (in place) ----------------
__global__ __launch_bounds__(256) void k_base(int* __restrict__ pcnt,
                                              const int* __restrict__ off) {
    int n = blockIdx.x * 256 + threadIdx.x;
    if (n >= N_NODES) return;
    unsigned b = (unsigned)n / SPAN, l = n - b * SPAN;
    int run = off[n];
#pragma unroll
    for (int s = 0; s < S0; ++s) {
        int idx = (b * S0 + s) * SPAN + l;
        int v = pcnt[idx];
        pcnt[idx] = run;
        run += v;
    }
}

// ---------------- K2d: fill CSR from buckets (LDS-ranked) ----------------
__global__ __launch_bounds__(256) void k_csrfill(const int* __restrict__ bsrc,
                                                 const int* __restrict__ bdst,
                                                 const int* __restrict__ bcount,
                                                 const int* __restrict__ pcnt, // bases
                                                 int* __restrict__ csr) {
    __shared__ int rank[SPAN];
    int b = blockIdx.x / S0, s = blockIdx.x % S0;
    for (int i = threadIdx.x; i < SPAN; i += 256)
        rank[i] = pcnt[(size_t)blockIdx.x * SPAN + i];
    __syncthreads();
    int tot = bcount[b];
    int lo = tot * s / S0, hi = tot * (s + 1) / S0;
    int base = b * SPAN;
    const int* bd = bdst + b * CAP;
    const int* bs = bsrc + b * CAP;
    for (int i = lo + threadIdx.x; i < hi; i += 256) {
        int d = bd[i];
        int r = atomicAdd(&rank[d - base], 1);
        csr[r] = bs[i];
    }
}

// ---------------- K3: p1 = dinv * (x @ W1) ----------------
__global__ __launch_bounds__(256) void k_gemm1(const float* __restrict__ x,
                                               const float* __restrict__ W1,
                                               const float* __restrict__ dinv,
                                               float* __restrict__ p1) {
    __shared__ float sW[IN_DIM * HID];
    for (int i = threadIdx.x; i < IN_DIM * HID; i += 256) sW[i] = W1[i];
    __syncthreads();

    int gid = blockIdx.x * 256 + threadIdx.x;
    int n = gid >> 4;
    int k = gid & 15;
    if (n >= N_NODES) return;

    const float* xr = x + (size_t)n * IN_DIM;
    float acc = 0.f;
#pragma unroll 8
    for (int j = 0; j < IN_DIM; ++j)
        acc = fmaf(xr[j], sW[j * HID + k], acc);

    p1[n * HID + k] = acc * dinv[n];
}

// ---------------- K4: node-parallel gather 1 (+relu/b1 and W2 fused) ----------------
__global__ __launch_bounds__(256) void k_gather1(const int* __restrict__ csr,
                                                 const int* __restrict__ off,
                                                 const int* __restrict__ cnt,
                                                 const float* __restrict__ p1,
                                                 const float* __restrict__ dinv,
                                                 const float* __restrict__ b1,
                                                 const float* __restrict__ W2,
                                                 float* __restrict__ p2b) {
    int gid = blockIdx.x * 256 + threadIdx.x;
    int n = gid >> 4;
    int k = gid & 15;
    if (n >= N_NODES) return;

    int base = off[n];
    int deg = cnt[n];
    float acc = 0.f;
    int j = 0;
    for (; j + 3 < deg; j += 4) {
        int s0 = csr[base + j + 0];
        int s1 = csr[base + j + 1];
        int s2 = csr[base + j + 2];
        int s3 = csr[base + j + 3];
        acc += p1[s0 * HID + k];
        acc += p1[s1 * HID + k];
        acc += p1[s2 * HID + k];
        acc += p1[s3 * HID + k];
    }
    for (; j < deg; ++j) acc += p1[csr[base + j] * HID + k];
    acc += p1[n * HID + k];                      // self-loop

    float di = dinv[n];
    float hval = fmaxf(fmaf(di, acc, b1[k]), 0.f);
    float hv = di * hval;
    float t0 = hv * W2[k * OUTC + 0];
    float t1 = hv * W2[k * OUTC + 1];
#pragma unroll
    for (int m = 1; m < HID; m <<= 1) {
        t0 += __shfl_xor(t0, m);
        t1 += __shfl_xor(t1, m);
    }
    if (k == 0) *(float2*)(p2b + n * OUTC) = make_float2(t0, t1);
}

// ---------------- K5: node-parallel gather 2 (+b2/log_softmax fused) ----------------
__global__ __launch_bounds__(256) void k_gather2(const int* __restrict__ csr,
                                                 const int* __restrict__ off,
                                                 const int* __restrict__ cnt,
                                                 const float* __restrict__ p2b,
                                                 const float* __restrict__ dinv,
                                                 const float* __restrict__ b2,
                                                 float* __restrict__ out) {
    int gid = blockIdx.x * 256 + threadIdx.x;
    int n = gid >> 4;
    int k = gid & 15;
    if (n >= N_NODES) return;

    int base = off[n];
    int deg = cnt[n];
    float a0 = 0.f, a1 = 0.f;
    for (int j = k; j < deg; j += 16) {
        int s = csr[base + j];
        float2 v = *(const float2*)(p2b + s * OUTC);
        a0 += v.x;
        a1 += v.y;
    }
    if (k == 0) {                                // self-loop
        float2 v = *(const float2*)(p2b + n * OUTC);
        a0 += v.x;
        a1 += v.y;
    }
#pragma unroll
    for (int m = 1; m < HID; m <<= 1) {
        a0 += __shfl_xor(a0, m);
        a1 += __shfl_xor(a1, m);
    }
    if (k == 0) {
        float di = dinv[n];
        float v0 = fmaf(di, a0, b2[0]);
        float v1 = fmaf(di, a1, b2[1]);
        float mx = fmaxf(v0, v1);
        float lse = mx + logf(expf(v0 - mx) + expf(v1 - mx));
        *(float2*)(out + n * OUTC) = make_float2(v0 - lse, v1 - lse);
    }
}

extern "C" void kernel_launch(void* const* d_in, const int* in_sizes, int n_in,
                              void* d_out, int out_size, void* d_ws, size_t ws_size,
                              hipStream_t stream) {
    const float* x  = (const float*)d_in[0];
    const int*   ei = (const int*)d_in[1];
    const float* W1 = (const float*)d_in[2];
    const float* b1 = (const float*)d_in[3];
    const float* W2 = (const float*)d_in[4];
    const float* b2 = (const float*)d_in[5];
    float* out = (float*)d_out;

    const int* src = ei;             // edge_index[0]
    const int* dst = ei + N_EDGES;   // edge_index[1]

    // workspace layout (4B elements)
    int* bc     = (int*)d_ws;                       // 32768
    int* bcount = bc + NBLK * NB;                   // 128
    int* bsum   = bcount + NB;                      // 49
    int* boff   = bsum + SCAN_NB;                   // 49
    int* bsrc   = (int*)(((uintptr_t)(boff + SCAN_NB) + 255) & ~(uintptr_t)255);
    int* bdst   = bsrc + NB * CAP;                  // 13.6 MB each
    int* pcnt   = bdst + NB * CAP;                  // S0*NB*SPAN = 800,768
    int* cnt    = pcnt + S0 * NB * SPAN;            // 100,000
    int* off    = cnt + N_NODES;                    // 100,000
    float* dinv = (float*)(off + N_NODES);          // 100,000
    int* csr    = (int*)(dinv + N_NODES);           // 12.8 MB
    float* p1   = (float*)(csr + N_EDGES);          // 6.4 MB
    float* p2b  = p1 + (size_t)N_NODES * HID;       // 0.8 MB

    k_count_bb <<<NBLK, 256, 0, stream>>>(dst, bc);
    k_scan_bb  <<<1, 128, 0, stream>>>(bc, bcount);
    k_fillbkt  <<<NBLK, 256, 0, stream>>>(src, dst, bc, bsrc, bdst);
    k_cnt_nodes<<<NB * S0, 256, 0, stream>>>(bdst, bcount, pcnt);
    k_cntsum   <<<(N_NODES + 255) / 256, 256, 0, stream>>>(pcnt, cnt, dinv);
    k_blocksum <<<SCAN_NB, 256, 0, stream>>>(cnt, bsum);
    k_scanb    <<<1, 64, 0, stream>>>(bsum, boff);
    k_offsets  <<<SCAN_NB, 256, 0, stream>>>(cnt, boff, off);
    k_base     <<<(N_NODES + 255) / 256, 256, 0, stream>>>(pcnt, off);
    k_csrfill  <<<NB * S0, 256, 0, stream>>>(bsrc, bdst, bcount, pcnt, csr);
    k_gemm1    <<<(N_NODES * 16 + 255) / 256, 256, 0, stream>>>(x, W1, dinv, p1);
    k_gather1  <<<(N_NODES * 16 + 255) / 256, 256, 0, stream>>>(csr, off, cnt, p1, dinv, b1, W2, p2b);
    k_gather2  <<<(N_NODES * 16 + 255) / 256, 256, 0, stream>>>(csr, off, cnt, p2b, dinv, b2, out);
}

// Round 13
// 178.779 us; speedup vs baseline: 2.9855x; 1.1129x over previous
//
#include <hip/hip_runtime.h>

#define N_NODES 100000
#define N_EDGES 3200000
#define IN_DIM  128
#define HID     16
#define OUTC    2

// bucket geometry
#define NB     128                    // dst-range buckets
#define SPAN   782                    // nodes per bucket (128*782 >= N)
#define CAP    26500                  // per-bucket capacity
#define NBLK   256                    // bucketing blocks
#define BLK_E  (N_EDGES / NBLK)       // 12500
#define S0     8                      // splits per bucket (hist + csrfill)

// node-scan geometry
#define SCAN_ELEMS 2048
#define SCAN_NB    49                 // ceil(100000/2048)

__device__ __forceinline__ unsigned short f2b(float f) {
    unsigned u = __float_as_uint(f);
    unsigned r = u + 0x7FFFu + ((u >> 16) & 1u);   // round-to-nearest-even
    return (unsigned short)(r >> 16);
}
__device__ __forceinline__ float b2f(unsigned short b) {
    return __uint_as_float(((unsigned)b) << 16);
}

// ---------------- K1a: per-(block,bucket) counts ----------------
__global__ __launch_bounds__(256) void k_count_bb(const int* __restrict__ dst,
                                                  int* __restrict__ bc) {
    __shared__ int h[NB];
    if (threadIdx.x < NB) h[threadIdx.x] = 0;
    __syncthreads();
    const int4* d4 = (const int4*)(dst + blockIdx.x * BLK_E);
    for (int i = threadIdx.x; i < BLK_E / 4; i += 256) {
        int4 v = d4[i];
        atomicAdd(&h[(unsigned)v.x / SPAN], 1);
        atomicAdd(&h[(unsigned)v.y / SPAN], 1);
        atomicAdd(&h[(unsigned)v.z / SPAN], 1);
        atomicAdd(&h[(unsigned)v.w / SPAN], 1);
    }
    __syncthreads();
    if (threadIdx.x < NB) bc[blockIdx.x * NB + threadIdx.x] = h[threadIdx.x];
}

// ---------------- K1b: parallel exclusive scan per bucket over blocks ----------------
__global__ __launch_bounds__(256) void k_scan_bb(int* __restrict__ bc,
                                                 int* __restrict__ bcount) {
    __shared__ int s[NBLK];
    int b = blockIdx.x;          // bucket
    int t = threadIdx.x;         // block index
    int v = bc[t * NB + b];
    s[t] = v;
    __syncthreads();
    for (int ofs = 1; ofs < NBLK; ofs <<= 1) {
        int u = (t >= ofs) ? s[t - ofs] : 0;
        __syncthreads();
        s[t] += u;
        __syncthreads();
    }
    bc[t * NB + b] = s[t] - v;   // exclusive
    if (t == NBLK - 1) bcount[b] = s[t];
}

// ---------------- K1c: fill buckets ----------------
__global__ __launch_bounds__(256) void k_fillbkt(const int* __restrict__ src,
                                                 const int* __restrict__ dst,
                                                 const int* __restrict__ bc,
                                                 int* __restrict__ bsrc,
                                                 int* __restrict__ bdst) {
    __shared__ int h[NB];
    __shared__ int gb[NB];
    if (threadIdx.x < NB) {
        h[threadIdx.x] = 0;
        gb[threadIdx.x] = threadIdx.x * CAP + bc[blockIdx.x * NB + threadIdx.x];
    }
    __syncthreads();
    const int4* d4 = (const int4*)(dst + blockIdx.x * BLK_E);
    const int4* s4 = (const int4*)(src + blockIdx.x * BLK_E);
    for (int i = threadIdx.x; i < BLK_E / 4; i += 256) {
        int4 dv = d4[i];
        int4 sv = s4[i];
        int b0 = (unsigned)dv.x / SPAN; int p0 = gb[b0] + atomicAdd(&h[b0], 1); bsrc[p0] = sv.x; bdst[p0] = dv.x;
        int b1 = (unsigned)dv.y / SPAN; int p1 = gb[b1] + atomicAdd(&h[b1], 1); bsrc[p1] = sv.y; bdst[p1] = dv.y;
        int b2 = (unsigned)dv.z / SPAN; int p2 = gb[b2] + atomicAdd(&h[b2], 1); bsrc[p2] = sv.z; bdst[p2] = dv.z;
        int b3 = (unsigned)dv.w / SPAN; int p3 = gb[b3] + atomicAdd(&h[b3], 1); bsrc[p3] = sv.w; bdst[p3] = dv.w;
    }
}

// ---------------- K2: per-node degree histogram, S0 splits ----------------
__global__ __launch_bounds__(256) void k_cnt_nodes(const int* __restrict__ bdst,
                                                   const int* __restrict__ bcount,
                                                   int* __restrict__ pcnt) {
    __shared__ int h[SPAN];
    int b = blockIdx.x / S0, s = blockIdx.x % S0;
    for (int i = threadIdx.x; i < SPAN; i += 256) h[i] = 0;
    __syncthreads();
    int tot = bcount[b];
    int lo = tot * s / S0, hi = tot * (s + 1) / S0;
    const int* bd = bdst + b * CAP;
    int base = b * SPAN;
    for (int i = lo + threadIdx.x; i < hi; i += 256)
        atomicAdd(&h[bd[i] - base], 1);
    __syncthreads();
    for (int j = threadIdx.x; j < SPAN; j += 256)
        pcnt[blockIdx.x * SPAN + j] = h[j];
}

// ---------------- K2b: cnt + dinv ----------------
__global__ __launch_bounds__(256) void k_cntsum(const int* __restrict__ pcnt,
                                                int* __restrict__ cnt,
                                                float* __restrict__ dinv) {
    int n = blockIdx.x * 256 + threadIdx.x;
    if (n >= N_NODES) return;
    unsigned b = (unsigned)n / SPAN, l = n - b * SPAN;
    int c = 0;
#pragma unroll
    for (int s = 0; s < S0; ++s)
        c += pcnt[(b * S0 + s) * SPAN + l];
    cnt[n] = c;
    dinv[n] = rsqrtf(1.0f + (float)c);   // + self-loop
}

// ---------------- node scan ----------------
__global__ __launch_bounds__(256) void k_blocksum(const int* __restrict__ cnt,
                                                  int* __restrict__ bsum) {
    __shared__ int s[256];
    int base = blockIdx.x * SCAN_ELEMS + threadIdx.x * 8;
    int t = 0;
#pragma unroll
    for (int i = 0; i < 8; ++i) {
        int idx = base + i;
        t += (idx < N_NODES) ? cnt[idx] : 0;
    }
    s[threadIdx.x] = t;
    __syncthreads();
    for (int ofs = 128; ofs > 0; ofs >>= 1) {
        if (threadIdx.x < ofs) s[threadIdx.x] += s[threadIdx.x + ofs];
        __syncthreads();
    }
    if (threadIdx.x == 0) bsum[blockIdx.x] = s[0];
}

__global__ __launch_bounds__(64) void k_scanb(const int* __restrict__ bsum,
                                              int* __restrict__ boff) {
    if (threadIdx.x == 0) {
        int run = 0;
        for (int b = 0; b < SCAN_NB; ++b) { boff[b] = run; run += bsum[b]; }
    }
}

// offsets + fused pcnt->csr-base conversion
__global__ __launch_bounds__(256) void k_offsets(const int* __restrict__ cnt,
                                                 const int* __restrict__ boff,
                                                 int* __restrict__ off,
                                                 int* __restrict__ pcnt) {
    __shared__ int s[256];
    int base = blockIdx.x * SCAN_ELEMS + threadIdx.x * 8;
    int c[8];
    int tsum = 0;
#pragma unroll
    for (int i = 0; i < 8; ++i) {
        int idx = base + i;
        c[i] = (idx < N_NODES) ? cnt[idx] : 0;
        tsum += c[i];
    }
    s[threadIdx.x] = tsum;
    __syncthreads();
    for (int ofs = 1; ofs < 256; ofs <<= 1) {
        int v = (threadIdx.x >= ofs) ? s[threadIdx.x - ofs] : 0;
        __syncthreads();
        s[threadIdx.x] += v;
        __syncthreads();
    }
    int tbase = boff[blockIdx.x] + s[threadIdx.x] - tsum;
    int run = 0;
#pragma unroll
    for (int i = 0; i < 8; ++i) {
        int idx = base + i;
        if (idx < N_NODES) {
            int o = tbase + run;
            off[idx] = o;
            unsigned bb = (unsigned)idx / SPAN, l = idx - bb * SPAN;
            int r2 = o;
#pragma unroll
            for (int sp = 0; sp < S0; ++sp) {
                int id2 = (bb * S0 + sp) * SPAN + l;
                int v = pcnt[id2];
                pcnt[id2] = r2;
                r2 += v;
            }
        }
        run += c[i];
    }
}

// ---------------- K2d: fill CSR from buckets (LDS-ranked) ----------------
__global__ __launch_bounds__(256) void k_csrfill(const int* __restrict__ bsrc,
                                                 const int* __restrict__ bdst,
                                                 const int* __restrict__ bcount,
                                                 const int* __restrict__ pcnt, // bases
                                                 int* __restrict__ csr) {
    __shared__ int rank[SPAN];
    int b = blockIdx.x / S0, s = blockIdx.x % S0;
    for (int i = threadIdx.x; i < SPAN; i += 256)
        rank[i] = pcnt[(size_t)blockIdx.x * SPAN + i];
    __syncthreads();
    int tot = bcount[b];
    int lo = tot * s / S0, hi = tot * (s + 1) / S0;
    int base = b * SPAN;
    const int* bd = bdst + b * CAP;
    const int* bs = bsrc + b * CAP;
    for (int i = lo + threadIdx.x; i < hi; i += 256) {
        int d = bd[i];
        int r = atomicAdd(&rank[d - base], 1);
        csr[r] = bs[i];
    }
}

// ---------------- K3: p1b(bf16) = dinv * (x @ W1) — one thread per node ----------------
__global__ __launch_bounds__(256) void k_gemm1(const float* __restrict__ x,
                                               const float* __restrict__ W1,
                                               const float* __restrict__ dinv,
                                               unsigned short* __restrict__ p1b) {
    int n = blockIdx.x * 256 + threadIdx.x;
    if (n >= N_NODES) return;

    float acc[HID];
#pragma unroll
    for (int k = 0; k < HID; ++k) acc[k] = 0.f;

    const float4* xr = (const float4*)(x + (size_t)n * IN_DIM);
#pragma unroll 4
    for (int q = 0; q < IN_DIM / 4; ++q) {
        float4 xv = xr[q];
        const float* wrow = W1 + q * 4 * HID;   // uniform -> scalar loads
#pragma unroll
        for (int k = 0; k < HID; ++k) acc[k] = fmaf(xv.x, wrow[0 * HID + k], acc[k]);
#pragma unroll
        for (int k = 0; k < HID; ++k) acc[k] = fmaf(xv.y, wrow[1 * HID + k], acc[k]);
#pragma unroll
        for (int k = 0; k < HID; ++k) acc[k] = fmaf(xv.z, wrow[2 * HID + k], acc[k]);
#pragma unroll
        for (int k = 0; k < HID; ++k) acc[k] = fmaf(xv.w, wrow[3 * HID + k], acc[k]);
    }

    float di = dinv[n];
    union { unsigned short us[HID]; uint4 v4[2]; } pk;
#pragma unroll
    for (int k = 0; k < HID; ++k) pk.us[k] = f2b(acc[k] * di);
    uint4* op = (uint4*)(p1b + (size_t)n * HID);
    op[0] = pk.v4[0];
    op[1] = pk.v4[1];
}

// ---------------- K4: node-parallel gather 1 (+relu/b1 and W2 fused) ----------------
__global__ __launch_bounds__(256) void k_gather1(const int* __restrict__ csr,
                                                 const int* __restrict__ off,
                                                 const int* __restrict__ cnt,
                                                 const unsigned short* __restrict__ p1b,
                                                 const float* __restrict__ dinv,
                                                 const float* __restrict__ b1,
                                                 const float* __restrict__ W2,
                                                 float* __restrict__ p2b) {
    int gid = blockIdx.x * 256 + threadIdx.x;
    int n = gid >> 4;
    int k = gid & 15;
    if (n >= N_NODES) return;

    int base = off[n];
    int deg = cnt[n];
    float acc = 0.f;
    int j = 0;
    for (; j + 3 < deg; j += 4) {
        int s0 = csr[base + j + 0];
        int s1 = csr[base + j + 1];
        int s2 = csr[base + j + 2];
        int s3 = csr[base + j + 3];
        float v0 = b2f(p1b[s0 * HID + k]);
        float v1 = b2f(p1b[s1 * HID + k]);
        float v2 = b2f(p1b[s2 * HID + k]);
        float v3 = b2f(p1b[s3 * HID + k]);
        acc += (v0 + v1) + (v2 + v3);
    }
    for (; j < deg; ++j) acc += b2f(p1b[csr[base + j] * HID + k]);
    acc += b2f(p1b[n * HID + k]);                // self-loop

    float di = dinv[n];
    float hval = fmaxf(fmaf(di, acc, b1[k]), 0.f);
    float hv = di * hval;
    float t0 = hv * W2[k * OUTC + 0];
    float t1 = hv * W2[k * OUTC + 1];
#pragma unroll
    for (int m = 1; m < HID; m <<= 1) {
        t0 += __shfl_xor(t0, m);
        t1 += __shfl_xor(t1, m);
    }
    if (k == 0) *(float2*)(p2b + n * OUTC) = make_float2(t0, t1);
}

// ---------------- K5: node-parallel gather 2 (+b2/log_softmax fused) ----------------
__global__ __launch_bounds__(256) void k_gather2(const int* __restrict__ csr,
                                                 const int* __restrict__ off,
                                                 const int* __restrict__ cnt,
                                                 const float* __restrict__ p2b,
                                                 const float* __restrict__ dinv,
                                                 const float* __restrict__ b2,
                                                 float* __restrict__ out) {
    int gid = blockIdx.x * 256 + threadIdx.x;
    int n = gid >> 4;
    int k = gid & 15;
    if (n >= N_NODES) return;

    int base = off[n];
    int deg = cnt[n];
    float a0 = 0.f, a1 = 0.f;
    for (int j = k; j < deg; j += 16) {
        int s = csr[base + j];
        float2 v = *(const float2*)(p2b + s * OUTC);
        a0 += v.x;
        a1 += v.y;
    }
    if (k == 0) {                                // self-loop
        float2 v = *(const float2*)(p2b + n * OUTC);
        a0 += v.x;
        a1 += v.y;
    }
#pragma unroll
    for (int m = 1; m < HID; m <<= 1) {
        a0 += __shfl_xor(a0, m);
        a1 += __shfl_xor(a1, m);
    }
    if (k == 0) {
        float di = dinv[n];
        float v0 = fmaf(di, a0, b2[0]);
        float v1 = fmaf(di, a1, b2[1]);
        float mx = fmaxf(v0, v1);
        float lse = mx + logf(expf(v0 - mx) + expf(v1 - mx));
        *(float2*)(out + n * OUTC) = make_float2(v0 - lse, v1 - lse);
    }
}

extern "C" void kernel_launch(void* const* d_in, const int* in_sizes, int n_in,
                              void* d_out, int out_size, void* d_ws, size_t ws_size,
                              hipStream_t stream) {
    const float* x  = (const float*)d_in[0];
    const int*   ei = (const int*)d_in[1];
    const float* W1 = (const float*)d_in[2];
    const float* b1 = (const float*)d_in[3];
    const float* W2 = (const float*)d_in[4];
    const float* b2 = (const float*)d_in[5];
    float* out = (float*)d_out;

    const int* src = ei;             // edge_index[0]
    const int* dst = ei + N_EDGES;   // edge_index[1]

    // workspace layout (4B elements)
    int* bc     = (int*)d_ws;                       // 32768
    int* bcount = bc + NBLK * NB;                   // 128
    int* bsum   = bcount + NB;                      // 49
    int* boff   = bsum + SCAN_NB;                   // 49
    int* bsrc   = (int*)(((uintptr_t)(boff + SCAN_NB) + 255) & ~(uintptr_t)255);
    int* bdst   = bsrc + NB * CAP;                  // 13.6 MB each
    int* pcnt   = bdst + NB * CAP;                  // S0*NB*SPAN = 800,768
    int* cnt    = pcnt + S0 * NB * SPAN;            // 100,000
    int* off    = cnt + N_NODES;                    // 100,000
    float* dinv = (float*)(off + N_NODES);          // 100,000
    int* csr    = (int*)(dinv + N_NODES);           // 12.8 MB
    unsigned short* p1b = (unsigned short*)(csr + N_EDGES);   // 3.2 MB
    float* p2b  = (float*)(p1b + (size_t)N_NODES * HID);      // 0.8 MB

    k_count_bb <<<NBLK, 256, 0, stream>>>(dst, bc);
    k_scan_bb  <<<NB, 256, 0, stream>>>(bc, bcount);
    k_fillbkt  <<<NBLK, 256, 0, stream>>>(src, dst, bc, bsrc, bdst);
    k_cnt_nodes<<<NB * S0, 256, 0, stream>>>(bdst, bcount, pcnt);
    k_cntsum   <<<(N_NODES + 255) / 256, 256, 0, stream>>>(pcnt, cnt, dinv);
    k_blocksum <<<SCAN_NB, 256, 0, stream>>>(cnt, bsum);
    k_scanb    <<<1, 64, 0, stream>>>(bsum, boff);
    k_offsets  <<<SCAN_NB, 256, 0, stream>>>(cnt, boff, off, pcnt);
    k_csrfill  <<<NB * S0, 256, 0, stream>>>(bsrc, bdst, bcount, pcnt, csr);
    k_gemm1    <<<(N_NODES + 255) / 256, 256, 0, stream>>>(x, W1, dinv, p1b);
    k_gather1  <<<(N_NODES * 16 + 255) / 256, 256, 0, stream>>>(csr, off, cnt, p1b, dinv, b1, W2, p2b);
    k_gather2  <<<(N_NODES * 16 + 255) / 256, 256, 0, stream>>>(csr, off, cnt, p2b, dinv, b2, out);
}

// Round 14
// 160.992 us; speedup vs baseline: 3.3153x; 1.1105x over previous
//
#include <hip/hip_runtime.h>

#define N_NODES 100000
#define N_EDGES 3200000
#define IN_DIM  128
#define HID     16
#define OUTC    2

// bucket geometry
#define NB     128                    // dst-range buckets
#define SPAN   782                    // nodes per bucket (128*782 >= N)
#define CAP    26500                  // per-bucket capacity
#define NBLK   256                    // bucketing blocks
#define BLK_E  (N_EDGES / NBLK)       // 12500
#define S0     8                      // splits per bucket (hist + csrfill)

// node-scan geometry
#define SCAN_ELEMS 2048
#define SCAN_NB    49                 // ceil(100000/2048)

__device__ __forceinline__ unsigned short f2b(float f) {
    unsigned u = __float_as_uint(f);
    unsigned r = u + 0x7FFFu + ((u >> 16) & 1u);   // round-to-nearest-even
    return (unsigned short)(r >> 16);
}
__device__ __forceinline__ float b2f(unsigned short b) {
    return __uint_as_float(((unsigned)b) << 16);
}

// ---------------- K1a: per-(block,bucket) counts ----------------
__global__ __launch_bounds__(256) void k_count_bb(const int* __restrict__ dst,
                                                  int* __restrict__ bc) {
    __shared__ int h[NB];
    if (threadIdx.x < NB) h[threadIdx.x] = 0;
    __syncthreads();
    const int4* d4 = (const int4*)(dst + blockIdx.x * BLK_E);
    for (int i = threadIdx.x; i < BLK_E / 4; i += 256) {
        int4 v = d4[i];
        atomicAdd(&h[(unsigned)v.x / SPAN], 1);
        atomicAdd(&h[(unsigned)v.y / SPAN], 1);
        atomicAdd(&h[(unsigned)v.z / SPAN], 1);
        atomicAdd(&h[(unsigned)v.w / SPAN], 1);
    }
    __syncthreads();
    if (threadIdx.x < NB) bc[blockIdx.x * NB + threadIdx.x] = h[threadIdx.x];
}

// ---------------- K1b: parallel exclusive scan per bucket over blocks ----------------
__global__ __launch_bounds__(256) void k_scan_bb(int* __restrict__ bc,
                                                 int* __restrict__ bcount) {
    __shared__ int s[NBLK];
    int b = blockIdx.x;          // bucket
    int t = threadIdx.x;         // block index
    int v = bc[t * NB + b];
    s[t] = v;
    __syncthreads();
    for (int ofs = 1; ofs < NBLK; ofs <<= 1) {
        int u = (t >= ofs) ? s[t - ofs] : 0;
        __syncthreads();
        s[t] += u;
        __syncthreads();
    }
    bc[t * NB + b] = s[t] - v;   // exclusive
    if (t == NBLK - 1) bcount[b] = s[t];
}

// ---------------- K1c: fill buckets ----------------
__global__ __launch_bounds__(256) void k_fillbkt(const int* __restrict__ src,
                                                 const int* __restrict__ dst,
                                                 const int* __restrict__ bc,
                                                 int* __restrict__ bsrc,
                                                 int* __restrict__ bdst) {
    __shared__ int h[NB];
    __shared__ int gb[NB];
    if (threadIdx.x < NB) {
        h[threadIdx.x] = 0;
        gb[threadIdx.x] = threadIdx.x * CAP + bc[blockIdx.x * NB + threadIdx.x];
    }
    __syncthreads();
    const int4* d4 = (const int4*)(dst + blockIdx.x * BLK_E);
    const int4* s4 = (const int4*)(src + blockIdx.x * BLK_E);
    for (int i = threadIdx.x; i < BLK_E / 4; i += 256) {
        int4 dv = d4[i];
        int4 sv = s4[i];
        int b0 = (unsigned)dv.x / SPAN; int p0 = gb[b0] + atomicAdd(&h[b0], 1); bsrc[p0] = sv.x; bdst[p0] = dv.x;
        int b1 = (unsigned)dv.y / SPAN; int p1 = gb[b1] + atomicAdd(&h[b1], 1); bsrc[p1] = sv.y; bdst[p1] = dv.y;
        int b2 = (unsigned)dv.z / SPAN; int p2 = gb[b2] + atomicAdd(&h[b2], 1); bsrc[p2] = sv.z; bdst[p2] = dv.z;
        int b3 = (unsigned)dv.w / SPAN; int p3 = gb[b3] + atomicAdd(&h[b3], 1); bsrc[p3] = sv.w; bdst[p3] = dv.w;
    }
}

// ---------------- K2: per-node degree histogram, S0 splits ----------------
__global__ __launch_bounds__(256) void k_cnt_nodes(const int* __restrict__ bdst,
                                                   const int* __restrict__ bcount,
                                                   int* __restrict__ pcnt) {
    __shared__ int h[SPAN];
    int b = blockIdx.x / S0, s = blockIdx.x % S0;
    for (int i = threadIdx.x; i < SPAN; i += 256) h[i] = 0;
    __syncthreads();
    int tot = bcount[b];
    int lo = tot * s / S0, hi = tot * (s + 1) / S0;
    const int* bd = bdst + b * CAP;
    int base = b * SPAN;
    for (int i = lo + threadIdx.x; i < hi; i += 256)
        atomicAdd(&h[bd[i] - base], 1);
    __syncthreads();
    for (int j = threadIdx.x; j < SPAN; j += 256)
        pcnt[blockIdx.x * SPAN + j] = h[j];
}

// ---------------- K2b: cnt + dinv ----------------
__global__ __launch_bounds__(256) void k_cntsum(const int* __restrict__ pcnt,
                                                int* __restrict__ cnt,
                                                float* __restrict__ dinv) {
    int n = blockIdx.x * 256 + threadIdx.x;
    if (n >= N_NODES) return;
    unsigned b = (unsigned)n / SPAN, l = n - b * SPAN;
    int c = 0;
#pragma unroll
    for (int s = 0; s < S0; ++s)
        c += pcnt[(b * S0 + s) * SPAN + l];
    cnt[n] = c;
    dinv[n] = rsqrtf(1.0f + (float)c);   // + self-loop
}

// ---------------- node scan ----------------
__global__ __launch_bounds__(256) void k_blocksum(const int* __restrict__ cnt,
                                                  int* __restrict__ bsum) {
    __shared__ int s[256];
    int base = blockIdx.x * SCAN_ELEMS + threadIdx.x * 8;
    int t = 0;
#pragma unroll
    for (int i = 0; i < 8; ++i) {
        int idx = base + i;
        t += (idx < N_NODES) ? cnt[idx] : 0;
    }
    s[threadIdx.x] = t;
    __syncthreads();
    for (int ofs = 128; ofs > 0; ofs >>= 1) {
        if (threadIdx.x < ofs) s[threadIdx.x] += s[threadIdx.x + ofs];
        __syncthreads();
    }
    if (threadIdx.x == 0) bsum[blockIdx.x] = s[0];
}

__global__ __launch_bounds__(64) void k_scanb(const int* __restrict__ bsum,
                                              int* __restrict__ boff) {
    if (threadIdx.x == 0) {
        int run = 0;
        for (int b = 0; b < SCAN_NB; ++b) { boff[b] = run; run += bsum[b]; }
    }
}

// offsets + fused pcnt->csr-base conversion
__global__ __launch_bounds__(256) void k_offsets(const int* __restrict__ cnt,
                                                 const int* __restrict__ boff,
                                                 int* __restrict__ off,
                                                 int* __restrict__ pcnt) {
    __shared__ int s[256];
    int base = blockIdx.x * SCAN_ELEMS + threadIdx.x * 8;
    int c[8];
    int tsum = 0;
#pragma unroll
    for (int i = 0; i < 8; ++i) {
        int idx = base + i;
        c[i] = (idx < N_NODES) ? cnt[idx] : 0;
        tsum += c[i];
    }
    s[threadIdx.x] = tsum;
    __syncthreads();
    for (int ofs = 1; ofs < 256; ofs <<= 1) {
        int v = (threadIdx.x >= ofs) ? s[threadIdx.x - ofs] : 0;
        __syncthreads();
        s[threadIdx.x] += v;
        __syncthreads();
    }
    int tbase = boff[blockIdx.x] + s[threadIdx.x] - tsum;
    int run = 0;
#pragma unroll
    for (int i = 0; i < 8; ++i) {
        int idx = base + i;
        if (idx < N_NODES) {
            int o = tbase + run;
            off[idx] = o;
            unsigned bb = (unsigned)idx / SPAN, l = idx - bb * SPAN;
            int r2 = o;
#pragma unroll
            for (int sp = 0; sp < S0; ++sp) {
                int id2 = (bb * S0 + sp) * SPAN + l;
                int v = pcnt[id2];
                pcnt[id2] = r2;
                r2 += v;
            }
        }
        run += c[i];
    }
}

// ---------------- K2d: fill CSR from buckets (LDS-ranked) ----------------
// SPLIT-MAJOR block indexing: b = blockIdx % NB, s = blockIdx / NB.
// All 8 split-blocks of bucket b share blockIdx ≡ b (mod 8) -> same XCD under
// round-robin dispatch -> the bucket's csr lines are dirtied in ONE L2 and
// written back whole (fixes the 7x partial-sector write amplification).
__global__ __launch_bounds__(256) void k_csrfill(const int* __restrict__ bsrc,
                                                 const int* __restrict__ bdst,
                                                 const int* __restrict__ bcount,
                                                 const int* __restrict__ pcnt, // bases
                                                 int* __restrict__ csr) {
    __shared__ int rank[SPAN];
    int b = blockIdx.x % NB, s = blockIdx.x / NB;
    for (int i = threadIdx.x; i < SPAN; i += 256)
        rank[i] = pcnt[(size_t)(b * S0 + s) * SPAN + i];
    __syncthreads();
    int tot = bcount[b];
    int lo = tot * s / S0, hi = tot * (s + 1) / S0;
    int base = b * SPAN;
    const int* bd = bdst + b * CAP;
    const int* bs = bsrc + b * CAP;
    for (int i = lo + threadIdx.x; i < hi; i += 256) {
        int d = bd[i];
        int r = atomicAdd(&rank[d - base], 1);
        csr[r] = bs[i];
    }
}

// ---------------- K3: p1b(bf16) = dinv * (x @ W1) — one thread per node ----------------
__global__ __launch_bounds__(256) void k_gemm1(const float* __restrict__ x,
                                               const float* __restrict__ W1,
                                               const float* __restrict__ dinv,
                                               unsigned short* __restrict__ p1b) {
    int n = blockIdx.x * 256 + threadIdx.x;
    if (n >= N_NODES) return;

    float acc[HID];
#pragma unroll
    for (int k = 0; k < HID; ++k) acc[k] = 0.f;

    const float4* xr = (const float4*)(x + (size_t)n * IN_DIM);
#pragma unroll 4
    for (int q = 0; q < IN_DIM / 4; ++q) {
        float4 xv = xr[q];
        const float* wrow = W1 + q * 4 * HID;   // uniform -> scalar loads
#pragma unroll
        for (int k = 0; k < HID; ++k) acc[k] = fmaf(xv.x, wrow[0 * HID + k], acc[k]);
#pragma unroll
        for (int k = 0; k < HID; ++k) acc[k] = fmaf(xv.y, wrow[1 * HID + k], acc[k]);
#pragma unroll
        for (int k = 0; k < HID; ++k) acc[k] = fmaf(xv.z, wrow[2 * HID + k], acc[k]);
#pragma unroll
        for (int k = 0; k < HID; ++k) acc[k] = fmaf(xv.w, wrow[3 * HID + k], acc[k]);
    }

    float di = dinv[n];
    union { unsigned short us[HID]; uint4 v4[2]; } pk;
#pragma unroll
    for (int k = 0; k < HID; ++k) pk.us[k] = f2b(acc[k] * di);
    uint4* op = (uint4*)(p1b + (size_t)n * HID);
    op[0] = pk.v4[0];
    op[1] = pk.v4[1];
}

// ---------------- K4: node-parallel gather 1 (+relu/b1 and W2 fused) ----------------
__global__ __launch_bounds__(256) void k_gather1(const int* __restrict__ csr,
                                                 const int* __restrict__ off,
                                                 const int* __restrict__ cnt,
                                                 const unsigned short* __restrict__ p1b,
                                                 const float* __restrict__ dinv,
                                                 const float* __restrict__ b1,
                                                 const float* __restrict__ W2,
                                                 float* __restrict__ p2b) {
    int gid = blockIdx.x * 256 + threadIdx.x;
    int n = gid >> 4;
    int k = gid & 15;
    if (n >= N_NODES) return;

    int base = off[n];
    int deg = cnt[n];
    float acc = 0.f;
    int j = 0;
    for (; j + 3 < deg; j += 4) {
        int s0 = csr[base + j + 0];
        int s1 = csr[base + j + 1];
        int s2 = csr[base + j + 2];
        int s3 = csr[base + j + 3];
        float v0 = b2f(p1b[s0 * HID + k]);
        float v1 = b2f(p1b[s1 * HID + k]);
        float v2 = b2f(p1b[s2 * HID + k]);
        float v3 = b2f(p1b[s3 * HID + k]);
        acc += (v0 + v1) + (v2 + v3);
    }
    for (; j < deg; ++j) acc += b2f(p1b[csr[base + j] * HID + k]);
    acc += b2f(p1b[n * HID + k]);                // self-loop

    float di = dinv[n];
    float hval = fmaxf(fmaf(di, acc, b1[k]), 0.f);
    float hv = di * hval;
    float t0 = hv * W2[k * OUTC + 0];
    float t1 = hv * W2[k * OUTC + 1];
#pragma unroll
    for (int m = 1; m < HID; m <<= 1) {
        t0 += __shfl_xor(t0, m);
        t1 += __shfl_xor(t1, m);
    }
    if (k == 0) *(float2*)(p2b + n * OUTC) = make_float2(t0, t1);
}

// ---------------- K5: node-parallel gather 2 (+b2/log_softmax fused) ----------------
__global__ __launch_bounds__(256) void k_gather2(const int* __restrict__ csr,
                                                 const int* __restrict__ off,
                                                 const int* __restrict__ cnt,
                                                 const float* __restrict__ p2b,
                                                 const float* __restrict__ dinv,
                                                 const float* __restrict__ b2,
                                                 float* __restrict__ out) {
    int gid = blockIdx.x * 256 + threadIdx.x;
    int n = gid >> 4;
    int k = gid & 15;
    if (n >= N_NODES) return;

    int base = off[n];
    int deg = cnt[n];
    float a0 = 0.f, a1 = 0.f;
    for (int j = k; j < deg; j += 16) {
        int s = csr[base + j];
        float2 v = *(const float2*)(p2b + s * OUTC);
        a0 += v.x;
        a1 += v.y;
    }
    if (k == 0) {                                // self-loop
        float2 v = *(const float2*)(p2b + n * OUTC);
        a0 += v.x;
        a1 += v.y;
    }
#pragma unroll
    for (int m = 1; m < HID; m <<= 1) {
        a0 += __shfl_xor(a0, m);
        a1 += __shfl_xor(a1, m);
    }
    if (k == 0) {
        float di = dinv[n];
        float v0 = fmaf(di, a0, b2[0]);
        float v1 = fmaf(di, a1, b2[1]);
        float mx = fmaxf(v0, v1);
        float lse = mx + logf(expf(v0 - mx) + expf(v1 - mx));
        *(float2*)(out + n * OUTC) = make_float2(v0 - lse, v1 - lse);
    }
}

extern "C" void kernel_launch(void* const* d_in, const int* in_sizes, int n_in,
                              void* d_out, int out_size, void* d_ws, size_t ws_size,
                              hipStream_t stream) {
    const float* x  = (const float*)d_in[0];
    const int*   ei = (const int*)d_in[1];
    const float* W1 = (const float*)d_in[2];
    const float* b1 = (const float*)d_in[3];
    const float* W2 = (const float*)d_in[4];
    const float* b2 = (const float*)d_in[5];
    float* out = (float*)d_out;

    const int* src = ei;             // edge_index[0]
    const int* dst = ei + N_EDGES;   // edge_index[1]

    // workspace layout (4B elements)
    int* bc     = (int*)d_ws;                       // 32768
    int* bcount = bc + NBLK * NB;                   // 128
    int* bsum   = bcount + NB;                      // 49
    int* boff   = bsum + SCAN_NB;                   // 49
    int* bsrc   = (int*)(((uintptr_t)(boff + SCAN_NB) + 255) & ~(uintptr_t)255);
    int* bdst   = bsrc + NB * CAP;                  // 13.6 MB each
    int* pcnt   = bdst + NB * CAP;                  // S0*NB*SPAN = 800,768
    int* cnt    = pcnt + S0 * NB * SPAN;            // 100,000
    int* off    = cnt + N_NODES;                    // 100,000
    float* dinv = (float*)(off + N_NODES);          // 100,000
    int* csr    = (int*)(dinv + N_NODES);           // 12.8 MB
    unsigned short* p1b = (unsigned short*)(csr + N_EDGES);   // 3.2 MB
    float* p2b  = (float*)(p1b + (size_t)N_NODES * HID);      // 0.8 MB

    k_count_bb <<<NBLK, 256, 0, stream>>>(dst, bc);
    k_scan_bb  <<<NB, 256, 0, stream>>>(bc, bcount);
    k_fillbkt  <<<NBLK, 256, 0, stream>>>(src, dst, bc, bsrc, bdst);
    k_cnt_nodes<<<NB * S0, 256, 0, stream>>>(bdst, bcount, pcnt);
    k_cntsum   <<<(N_NODES + 255) / 256, 256, 0, stream>>>(pcnt, cnt, dinv);
    k_blocksum <<<SCAN_NB, 256, 0, stream>>>(cnt, bsum);
    k_scanb    <<<1, 64, 0, stream>>>(bsum, boff);
    k_offsets  <<<SCAN_NB, 256, 0, stream>>>(cnt, boff, off, pcnt);
    k_csrfill  <<<NB * S0, 256, 0, stream>>>(bsrc, bdst, bcount, pcnt, csr);
    k_gemm1    <<<(N_NODES + 255) / 256, 256, 0, stream>>>(x, W1, dinv, p1b);
    k_gather1  <<<(N_NODES * 16 + 255) / 256, 256, 0, stream>>>(csr, off, cnt, p1b, dinv, b1, W2, p2b);
    k_gather2  <<<(N_NODES * 16 + 255) / 256, 256, 0, stream>>>(csr, off, cnt, p2b, dinv, b2, out);
}